// Round 5
// baseline (2905.816 us; speedup 1.0000x reference)
//
#include <hip/hip_runtime.h>

// GRU B=64, T=512, IN=128, H=512, L=2, OUT=1 (fp32 in/out).
// R10: XCD-local recurrence exchange.
//   Counters said R9's period (8070 cyc/step, MfmaUtil 12%, VALUBusy 16%)
//   is dominated by MALL round-trips of the per-step h exchange (agent/sc1
//   ops bypass per-XCD L2). Changes, all sync-protocol-preserving:
//   - Block remap g=idx&7, cb=idx>>3: each (layer,m) group of 32 blocks
//     lands on ONE XCD (dispatch round-robin model: block p -> XCD p%8).
//     Mapping is a perf heuristic only; correctness never depends on it.
//   - Producer dual-store: plain volatile store (write-back -> fresh line
//     in the SHARED XCD L2) then sc1 agent store (through to MALL; keeps
//     cross-XCD pipe + any mis-mapping correct).
//   - fix4 hierarchical retry: sc0 L2 probe (fast when co-located) then
//     authoritative sc1 MALL pair (always correct). MALL probe rate <= R9.
//   - L1 fixes intra-XCD recurrence chunks (hseq1) before pipe (hseq0).
// R7/R8 lesson stands: serialized, rate-limited retries only; no wide
// parallel retry without backoff (fabric storm: WRITE 134MB->40GB).

constexpr int Bb = 64, Tt = 512, DIN = 128, Hh = 512;
constexpr int BH = Bb * Hh;
constexpr int S0 = 644;    // LDS A-row stride (u32), layer0: 128 x + 512 h + 4 pad
constexpr int S1 = 1028;   // layer1: 512 h0 + 512 h1 + 4 pad
constexpr int PR = 20;     // partials row stride: conflict-free (2-way) writes

typedef float  f32x4  __attribute__((ext_vector_type(4)));
typedef short  bf16x8 __attribute__((ext_vector_type(8)));
typedef int    i32x4  __attribute__((ext_vector_type(4)));
typedef unsigned long long u64;

#define MFMA16 __builtin_amdgcn_mfma_f32_16x16x32_bf16

__device__ __forceinline__ unsigned rne_bf16(unsigned xb){
    return (xb + 0x7FFFu + ((xb >> 16) & 1u)) >> 16;
}
__device__ __forceinline__ unsigned pack_split(float x){
    unsigned hb = rne_bf16(__float_as_uint(x));
    float hf = __uint_as_float(hb << 16);
    unsigned lb = rne_bf16(__float_as_uint(x - hf));
    return (hb << 16) | lb;
}
__device__ __forceinline__ float unpack_f32(unsigned u){
    return __uint_as_float(u & 0xFFFF0000u) + __uint_as_float(u << 16);
}

union FragU { unsigned w[4]; bf16x8 v; };

__device__ __forceinline__ void make_wfrag(const float* p, bf16x8& wh, bf16x8& wl){
    FragU hi, lo;
#pragma unroll
    for (int i = 0; i < 4; ++i){
        unsigned pa = pack_split(p[2*i]), pb = pack_split(p[2*i+1]);
        hi.w[i] = (pa >> 16) | (pb & 0xFFFF0000u);
        lo.w[i] = (pa & 0xFFFFu) | (pb << 16);
    }
    wh = hi.v; wl = lo.v;
}
// hi word = [b3,b2,a3,a2], lo word = [b1,b0,a1,a0] -- one v_perm_b32 each.
__device__ __forceinline__ void make_afrag(const unsigned* u, bf16x8& ah, bf16x8& al){
    FragU hi, lo;
#pragma unroll
    for (int i = 0; i < 4; ++i){
        unsigned a = u[2*i], b = u[2*i+1];
        hi.w[i] = __builtin_amdgcn_perm(b, a, 0x07060302u);
        lo.w[i] = __builtin_amdgcn_perm(b, a, 0x05040100u);
    }
    ah = hi.v; al = lo.v;
}

__device__ __forceinline__ u64 ald64(const u64* p){
    return __hip_atomic_load(p, __ATOMIC_RELAXED, __HIP_MEMORY_SCOPE_AGENT);
}
// sc0 load: bypass L1, served by this XCD's shared L2 (fast path when the
// producer is co-located and its plain store deposited the fresh line).
__device__ __forceinline__ i32x4 ld128_sc0(const unsigned* p){
    i32x4 r;
    asm volatile("global_load_dwordx4 %0, %1, off sc0\n\t"
                 "s_waitcnt vmcnt(0)"
                 : "=v"(r) : "v"(p) : "memory");
    return r;
}
// dual store: plain write-back (fresh line in local shared L2) then agent
// sc1 store (write-through to MALL -- the always-correct copy).
__device__ __forceinline__ void st64_dual(u64* p, u64 v){
    *(volatile u64*)p = v;
    __hip_atomic_store(p, v, __ATOMIC_RELAXED, __HIP_MEMORY_SCOPE_AGENT);
}

// all 4 words must have bit0 == tag
__device__ __forceinline__ bool bad4(const i32x4& v, unsigned tag){
    unsigned x = ((unsigned)v[0] ^ tag) | ((unsigned)v[1] ^ tag)
               | ((unsigned)v[2] ^ tag) | ((unsigned)v[3] ^ tag);
    return (x & 1u) != 0u;
}
// retry path, SERIALIZED per chunk (fabric rate-limiter -- R7/R8 lesson).
// Each iteration: cheap shared-L2 probe (sc0), then authoritative MALL
// probe (sc1 agent). MALL probe rate is no higher than R9's.
__device__ __forceinline__ void fix4(const unsigned* p, unsigned tag, i32x4& v){
    if (bad4(v, tag)){
        for (;;){
            v = ld128_sc0(p);
            if (!bad4(v, tag)) break;
            u64 a = ald64((const u64*)p);
            u64 b = ald64((const u64*)p + 1);
            v[0] = (int)(unsigned)a; v[1] = (int)(unsigned)(a >> 32);
            v[2] = (int)(unsigned)b; v[3] = (int)(unsigned)(b >> 32);
            if (!bad4(v, tag)) break;
            __builtin_amdgcn_s_sleep(1);
        }
    }
}

template<bool BIG>
__global__ __launch_bounds__(512, 1) void gru_main(
    const float* __restrict__ X,
    const float* __restrict__ Wih0, const float* __restrict__ Whh0,
    const float* __restrict__ bih0, const float* __restrict__ bhh0,
    const float* __restrict__ Wih1, const float* __restrict__ Whh1,
    const float* __restrict__ bih1, const float* __restrict__ bhh1,
    const float* __restrict__ fcW, const float* __restrict__ fcb,
    float* __restrict__ out,
    unsigned* hseq0, unsigned* hseq1)
{
    // Kill stale clean L1/L2 lines left from the previous graph replay.
    __builtin_amdgcn_fence(__ATOMIC_ACQUIRE, "agent");

    __shared__ unsigned Alds[16 * S1];
    __shared__ float P[8][3][16 * PR];
    __shared__ unsigned hout[256];

    const int tid  = threadIdx.x;
    const int lane = tid & 63;
    const int w    = tid >> 6;
    // XCD-gather remap: group g = (layer,m) -> all 32 of its col-blocks
    // share blockIdx%8, i.e. (under round-robin dispatch) one XCD's L2.
    const int g  = (int)blockIdx.x & 7;
    const int cb = (int)blockIdx.x >> 3;   // col-block 0..31
    const bool isL1 = g >= 4;
    const int m  = g & 3;                  // batch tile 0..3
    const int c0 = cb * 16;
    const int STR  = isL1 ? S1 : S0;
    const int HOFF = isL1 ? 512 : 128;

    const bool active = isL1 || (w < 5);   // layer0 K=640 -> 5 waves x 128

    // ---- register-resident weight fragments (hi/lo split-bf16) ----
    bf16x8 whi[4][3], wlo[4][3];
    if (active){
        const int n = lane & 15;
#pragma unroll
        for (int ks = 0; ks < 4; ++ks){
            int kq = w * 128 + ks * 32 + (lane >> 4) * 8;
            const float* src; long kloc, rowlen;
            if (isL1){
                if (kq < 512){ src = Wih1; kloc = kq; } else { src = Whh1; kloc = kq - 512; }
                rowlen = 512;
            } else {
                if (kq < 128){ src = Wih0; kloc = kq; rowlen = 128; }
                else         { src = Whh0; kloc = kq - 128; rowlen = 512; }
            }
#pragma unroll
            for (int g2 = 0; g2 < 3; ++g2){
                long row = (long)g2 * Hh + c0 + n;
                make_wfrag(src + row * rowlen + kloc, whi[ks][g2], wlo[ks][g2]);
            }
        }
    }
    // ---- biases for epilogue ----
    float Br = 0.f, Bz = 0.f, Bin = 0.f, Bhn = 0.f;
    if (tid < 256){
        int c = c0 + (tid & 15);
        const float* bi = isL1 ? bih1 : bih0;
        const float* bh = isL1 ? bhh1 : bhh0;
        Br  = bi[c] + bh[c];
        Bz  = bi[Hh + c] + bh[Hh + c];
        Bin = bi[2*Hh + c];
        Bhn = bh[2*Hh + c];
    }

    for (int t = 0; t < Tt; ++t){
        // ---- staging: all 8 waves, speculative loads + validity fix-up ----
        if (isL1){
            const unsigned* s0 = hseq0 + ((long)t * Bb + m*16) * (long)Hh;
            long r1 = BIG ? (long)(t-1) * BH : (long)((t-1) & 1) * BH;
            const unsigned* s1 = hseq1 + r1 + (long)(m*16) * Hh;
            unsigned tag1 = BIG ? 1u : (1u - (((unsigned)(t-1) >> 1) & 1u));
            const unsigned* a0[4]; const unsigned* a1[4];
            i32x4 v0[4], v1[4];
#pragma unroll
            for (int it = 0; it < 4; ++it){
                int j = it*512 + tid; int row = j >> 7, col = (j & 127) * 4;
                a0[it] = s0 + (long)row * Hh + col;
                v0[it] = *(const i32x4*)a0[it];
            }
            if (t > 0){
#pragma unroll
                for (int it = 0; it < 4; ++it){
                    int j = it*512 + tid; int row = j >> 7, col = (j & 127) * 4;
                    a1[it] = s1 + (long)row * Hh + col;
                    v1[it] = *(const i32x4*)a1[it];
                }
            }
            // fix the intra-XCD recurrence chunks (hseq1) FIRST (fast L2
            // path), letting the cross-XCD pipe chunks (hseq0) age.
            if (t > 0){
#pragma unroll
                for (int it = 0; it < 4; ++it) fix4(a1[it], tag1, v1[it]);
            } else {
#pragma unroll
                for (int it = 0; it < 4; ++it) v1[it] = i32x4{0,0,0,0};
            }
#pragma unroll
            for (int it = 0; it < 4; ++it) fix4(a0[it], 1u, v0[it]);
#pragma unroll
            for (int it = 0; it < 4; ++it){
                int j = it*512 + tid; int row = j >> 7, col = (j & 127) * 4;
                *(i32x4*)(Alds + row * S1 + col) = v0[it];
                *(i32x4*)(Alds + row * S1 + 512 + col) = v1[it];
            }
        } else {
            // X[t] fp32 (cached input) -> pack on the fly
            {
                int row = tid >> 5, c4 = (tid & 31) * 4;
                f32x4 xv = *(const f32x4*)(X + ((long)(m*16 + row) * Tt + t) * DIN + c4);
                i32x4 pv;
                pv[0] = (int)pack_split(xv[0]);
                pv[1] = (int)pack_split(xv[1]);
                pv[2] = (int)pack_split(xv[2]);
                pv[3] = (int)pack_split(xv[3]);
                *(i32x4*)(Alds + row * S0 + c4) = pv;
            }
            if (t > 0){
                const unsigned* s0 = hseq0 + ((long)(t-1) * Bb + m*16) * (long)Hh;
                const unsigned* a0[4]; i32x4 v0[4];
#pragma unroll
                for (int it = 0; it < 4; ++it){
                    int j = it*512 + tid; int row = j >> 7, col = (j & 127) * 4;
                    a0[it] = s0 + (long)row * Hh + col;
                    v0[it] = *(const i32x4*)a0[it];
                }
#pragma unroll
                for (int it = 0; it < 4; ++it) fix4(a0[it], 1u, v0[it]);
#pragma unroll
                for (int it = 0; it < 4; ++it){
                    int j = it*512 + tid; int row = j >> 7, col = (j & 127) * 4;
                    *(i32x4*)(Alds + row * S0 + 128 + col) = v0[it];
                }
            } else {
#pragma unroll
                for (int it = 0; it < 8; ++it){
                    int j = it*512 + tid;
                    *(u64*)(Alds + (j >> 8) * S0 + 128 + (j & 255) * 2) = 0ULL;
                }
            }
        }
        __syncthreads();

        // ---- MFMA: this wave's K-slice, tiles {r, z, nx-or-nh} ----
        if (active){
            f32x4 a0 = {0.f,0.f,0.f,0.f}, a1 = a0, a2 = a0;
            const unsigned* arow = Alds + (lane & 15) * STR + w * 128 + (lane >> 4) * 8;
#pragma unroll
            for (int ks = 0; ks < 4; ++ks){
                unsigned uu[8];
                *(i32x4*)&uu[0] = *(const i32x4*)(arow + ks*32);
                *(i32x4*)&uu[4] = *(const i32x4*)(arow + ks*32 + 4);
                bf16x8 ah, al; make_afrag(uu, ah, al);
                a0 = MFMA16(ah, whi[ks][0], a0, 0,0,0);
                a0 = MFMA16(ah, wlo[ks][0], a0, 0,0,0);
                a0 = MFMA16(al, whi[ks][0], a0, 0,0,0);
                a1 = MFMA16(ah, whi[ks][1], a1, 0,0,0);
                a1 = MFMA16(ah, wlo[ks][1], a1, 0,0,0);
                a1 = MFMA16(al, whi[ks][1], a1, 0,0,0);
                a2 = MFMA16(ah, whi[ks][2], a2, 0,0,0);
                a2 = MFMA16(ah, wlo[ks][2], a2, 0,0,0);
                a2 = MFMA16(al, whi[ks][2], a2, 0,0,0);
            }
            int q = lane >> 4, n = lane & 15;
#pragma unroll
            for (int r4 = 0; r4 < 4; ++r4){
                int idx = (q*4 + r4)*PR + n;
                P[w][0][idx] = a0[r4];
                P[w][1][idx] = a1[r4];
                P[w][2][idx] = a2[r4];
            }
        }
        __syncthreads();

        // ---- reduce partials + gates -> tagged packed h into LDS ----
        unsigned wtag = isL1 ? (BIG ? 1u : (1u - (((unsigned)t >> 1) & 1u))) : 1u;
        if (tid < 256){
            int bm = tid >> 4, n = tid & 15;
            int idx = bm * PR + n;
            float sr, sz, snx, snh;
            if (isL1){
                sr  = P[0][0][idx]+P[1][0][idx]+P[2][0][idx]+P[3][0][idx]
                    + P[4][0][idx]+P[5][0][idx]+P[6][0][idx]+P[7][0][idx];
                sz  = P[0][1][idx]+P[1][1][idx]+P[2][1][idx]+P[3][1][idx]
                    + P[4][1][idx]+P[5][1][idx]+P[6][1][idx]+P[7][1][idx];
                snx = P[0][2][idx]+P[1][2][idx]+P[2][2][idx]+P[3][2][idx];
                snh = P[4][2][idx]+P[5][2][idx]+P[6][2][idx]+P[7][2][idx];
            } else {
                sr  = P[0][0][idx]+P[1][0][idx]+P[2][0][idx]+P[3][0][idx]+P[4][0][idx];
                sz  = P[0][1][idx]+P[1][1][idx]+P[2][1][idx]+P[3][1][idx]+P[4][1][idx];
                snx = P[0][2][idx];
                snh = P[1][2][idx]+P[2][2][idx]+P[3][2][idx]+P[4][2][idx];
            }
            float r  = 1.f/(1.f + __expf(-(sr + Br)));
            float z  = 1.f/(1.f + __expf(-(sz + Bz)));
            float ee = __expf(2.f*(snx + Bin + r*(snh + Bhn)));
            float nn = 1.f - 2.f/(ee + 1.f);
            float hp = unpack_f32(Alds[bm*STR + HOFF + c0 + n]);
            float hnew = (1.f - z)*nn + z*hp;
            hout[tid] = (pack_split(hnew) & ~1u) | wtag;   // hout[bm*16 + n]
        }
        __syncthreads();

        // ---- dual stores (plain -> shared L2, sc1 -> MALL); no ack wait ----
        if (tid < 128){
            int bm = tid >> 3, k = (tid & 7) * 2;
            u64 v = (u64)hout[bm*16 + k] | ((u64)hout[bm*16 + k + 1] << 32);
            unsigned* base = isL1
                ? hseq1 + (BIG ? (long)t * BH : (long)(t & 1) * BH)
                : hseq0 + (long)t * BH;
            st64_dual((u64*)(base + (long)(m*16 + bm) * Hh + c0 + k), v);
        }
    }

    // ---- FC epilogue: one layer1 block per m, validated reads ----
    if (isL1 && cb == 31){
        unsigned ftag = BIG ? 1u : (1u - (((unsigned)(Tt-1) >> 1) & 1u));
        const unsigned* hb = hseq1 + (BIG ? (long)(Tt-1) * BH : (long)((Tt-1) & 1) * BH);
        int half = lane >> 5, l5 = lane & 31;
        int b = m*16 + w*2 + half;
        const u64* hrow = (const u64*)(hb + (long)b * Hh);
        float p = 0.f;
#pragma unroll
        for (int i = 0; i < 8; ++i){
            int k = l5 + 32*i;
            u64 v = ald64(hrow + k);
            while (((((unsigned)v ^ ftag) | ((unsigned)(v >> 32) ^ ftag)) & 1u) != 0u){
                __builtin_amdgcn_s_sleep(1);
                v = ald64(hrow + k);
            }
            p += unpack_f32((unsigned)v) * fcW[2*k]
               + unpack_f32((unsigned)(v >> 32)) * fcW[2*k+1];
        }
#pragma unroll
        for (int off = 16; off > 0; off >>= 1) p += __shfl_xor(p, off);
        if (l5 == 0) out[b] = p + fcb[0];
    }
}

extern "C" void kernel_launch(void* const* d_in, const int* in_sizes, int n_in,
                              void* d_out, int out_size, void* d_ws, size_t ws_size,
                              hipStream_t stream) {
    const float* X    = (const float*)d_in[0];
    const float* Wih0 = (const float*)d_in[1];
    const float* Whh0 = (const float*)d_in[2];
    const float* bih0 = (const float*)d_in[3];
    const float* bhh0 = (const float*)d_in[4];
    const float* Wih1 = (const float*)d_in[5];
    const float* Whh1 = (const float*)d_in[6];
    const float* bih1 = (const float*)d_in[7];
    const float* bhh1 = (const float*)d_in[8];
    const float* fcW  = (const float*)d_in[9];
    const float* fcb  = (const float*)d_in[10];
    float* out = (float*)d_out;

    // ws: hseq0 64 MiB | hseq1 64 MiB (BIG) or 256 KiB ring. No flags, no memset:
    // harness poisons ws to 0xAA (bit0=0 = invalid) before every launch.
    unsigned* hseq0 = (unsigned*)d_ws;
    unsigned* hseq1 = hseq0 + (long)Tt * BH;
    size_t need_big = (size_t)2 * Tt * BH * 4;    // 128 MiB
    bool big = ws_size >= need_big;

    if (big)
        gru_main<true><<<256, 512, 0, stream>>>(X, Wih0, Whh0, bih0, bhh0,
                                                Wih1, Whh1, bih1, bhh1, fcW, fcb,
                                                out, hseq0, hseq1);
    else
        gru_main<false><<<256, 512, 0, stream>>>(X, Wih0, Whh0, bih0, bhh0,
                                                 Wih1, Whh1, bih1, bhh1, fcW, fcb,
                                                 out, hseq0, hseq1);
}

// Round 8
// 1934.746 us; speedup vs baseline: 1.5019x; 1.5019x over previous
//
#include <hip/hip_runtime.h>

// GRU B=64, T=512, IN=128, H=512, L=2, OUT=1 (fp32 in/out).
// R11 (2nd resubmit; Rounds 6+7 both GPUAcquisitionTimeout, never ran):
// register-direct A-fragments -- no LDS staging, no staging barrier.
//   Key observation: MFMA K-slices are DISJOINT across waves, so each lane
//   can load exactly its own A-fragments (row=lane&15, col=w*128+(lane>>4)*8
//   +ks*32 -- same formula the old LDS read used) straight from global into
//   registers, fix4 them, and MFMA immediately. Removes barrier #1, all
//   A-LDS traffic (staging writes + ds_read_b128 -> bank conflicts), and
//   decouples wave progress: L1 waves 4-7 (own recurrence, early) MFMA while
//   waves 0-3 spin on the L0 pipe; L0 wave 0 (X-only) never waits.
//   Gates keep h_prev in a register (proven R8) and store tagged u32 direct;
//   2 barriers remain: P-reduce + post-gate (guards P reuse across t).
//   R10 lesson: XCD-gather remap + sc0 probe + dual store = 1.7x REGRESSION
//   (single-L2 serialization + extra probe RTT); reverted to R9 mapping.
//   R7/R8 lesson stands: retries stay SERIALIZED per chunk (rate limiter).

constexpr int Bb = 64, Tt = 512, DIN = 128, Hh = 512;
constexpr int BH = Bb * Hh;
constexpr int PR = 20;     // partials row stride: 2-way (free) write conflicts

typedef float  f32x4  __attribute__((ext_vector_type(4)));
typedef short  bf16x8 __attribute__((ext_vector_type(8)));
typedef int    i32x4  __attribute__((ext_vector_type(4)));
typedef unsigned long long u64;

#define MFMA16 __builtin_amdgcn_mfma_f32_16x16x32_bf16

__device__ __forceinline__ unsigned rne_bf16(unsigned xb){
    return (xb + 0x7FFFu + ((xb >> 16) & 1u)) >> 16;
}
__device__ __forceinline__ unsigned pack_split(float x){
    unsigned hb = rne_bf16(__float_as_uint(x));
    float hf = __uint_as_float(hb << 16);
    unsigned lb = rne_bf16(__float_as_uint(x - hf));
    return (hb << 16) | lb;
}
__device__ __forceinline__ float unpack_f32(unsigned u){
    return __uint_as_float(u & 0xFFFF0000u) + __uint_as_float(u << 16);
}

union FragU { unsigned w[4]; bf16x8 v; };

__device__ __forceinline__ void make_wfrag(const float* p, bf16x8& wh, bf16x8& wl){
    FragU hi, lo;
#pragma unroll
    for (int i = 0; i < 4; ++i){
        unsigned pa = pack_split(p[2*i]), pb = pack_split(p[2*i+1]);
        hi.w[i] = (pa >> 16) | (pb & 0xFFFF0000u);
        lo.w[i] = (pa & 0xFFFFu) | (pb << 16);
    }
    wh = hi.v; wl = lo.v;
}
// hi word = [b3,b2,a3,a2], lo word = [b1,b0,a1,a0] -- one v_perm_b32 each.
__device__ __forceinline__ void make_afrag(const unsigned* u, bf16x8& ah, bf16x8& al){
    FragU hi, lo;
#pragma unroll
    for (int i = 0; i < 4; ++i){
        unsigned a = u[2*i], b = u[2*i+1];
        hi.w[i] = __builtin_amdgcn_perm(b, a, 0x07060302u);
        lo.w[i] = __builtin_amdgcn_perm(b, a, 0x05040100u);
    }
    ah = hi.v; al = lo.v;
}

__device__ __forceinline__ u64 ald64(const u64* p){
    return __hip_atomic_load(p, __ATOMIC_RELAXED, __HIP_MEMORY_SCOPE_AGENT);
}
__device__ __forceinline__ void ast32(unsigned* p, unsigned v){
    __hip_atomic_store(p, v, __ATOMIC_RELAXED, __HIP_MEMORY_SCOPE_AGENT);
}

// all 4 words must have bit0 == tag
__device__ __forceinline__ bool bad4(const i32x4& v, unsigned tag){
    unsigned x = ((unsigned)v[0] ^ tag) | ((unsigned)v[1] ^ tag)
               | ((unsigned)v[2] ^ tag) | ((unsigned)v[3] ^ tag);
    return (x & 1u) != 0u;
}
// retry path: bypass stale cached lines via IF (agent) loads.
// SERIALIZED per chunk on purpose -- fabric rate-limiter (R7/R8 lesson).
__device__ __forceinline__ void fix4(const unsigned* p, unsigned tag, i32x4& v){
    if (bad4(v, tag)){
        for (;;){
            u64 a = ald64((const u64*)p);
            u64 b = ald64((const u64*)p + 1);
            v[0] = (int)(unsigned)a; v[1] = (int)(unsigned)(a >> 32);
            v[2] = (int)(unsigned)b; v[3] = (int)(unsigned)(b >> 32);
            if (!bad4(v, tag)) break;
            __builtin_amdgcn_s_sleep(1);
        }
    }
}

template<bool BIG>
__global__ __launch_bounds__(512, 1) void gru_main(
    const float* __restrict__ X,
    const float* __restrict__ Wih0, const float* __restrict__ Whh0,
    const float* __restrict__ bih0, const float* __restrict__ bhh0,
    const float* __restrict__ Wih1, const float* __restrict__ Whh1,
    const float* __restrict__ bih1, const float* __restrict__ bhh1,
    const float* __restrict__ fcW, const float* __restrict__ fcb,
    float* __restrict__ out,
    unsigned* hseq0, unsigned* hseq1)
{
    // Kill stale clean L1/L2 lines left from the previous graph replay.
    __builtin_amdgcn_fence(__ATOMIC_ACQUIRE, "agent");

    __shared__ float P[8][3][16 * PR];

    const int tid  = threadIdx.x;
    const int lane = tid & 63;
    const int w    = tid >> 6;
    const bool isL1 = blockIdx.x >= 128;
    const int lb = isL1 ? (int)blockIdx.x - 128 : (int)blockIdx.x;
    const int m  = lb >> 5;                // batch tile 0..3
    const int cb = lb & 31;                // col-block 0..31
    const int c0 = cb * 16;

    const bool active = isL1 || (w < 5);   // layer0 K=640 -> 5 waves x 128
    const int r = lane & 15, q = lane >> 4;

    // ---- register-resident weight fragments (hi/lo split-bf16) ----
    bf16x8 whi[4][3], wlo[4][3];
    if (active){
#pragma unroll
        for (int ks = 0; ks < 4; ++ks){
            int kq = w * 128 + ks * 32 + q * 8;
            const float* src; long kloc, rowlen;
            if (isL1){
                if (kq < 512){ src = Wih1; kloc = kq; } else { src = Whh1; kloc = kq - 512; }
                rowlen = 512;
            } else {
                if (kq < 128){ src = Wih0; kloc = kq; rowlen = 128; }
                else         { src = Whh0; kloc = kq - 128; rowlen = 512; }
            }
#pragma unroll
            for (int g2 = 0; g2 < 3; ++g2){
                long row = (long)g2 * Hh + c0 + r;
                make_wfrag(src + row * rowlen + kloc, whi[ks][g2], wlo[ks][g2]);
            }
        }
    }
    // ---- biases for gate phase ----
    float Br = 0.f, Bz = 0.f, Bin = 0.f, Bhn = 0.f;
    if (tid < 256){
        int c = c0 + (tid & 15);
        const float* bi = isL1 ? bih1 : bih0;
        const float* bh = isL1 ? bhh1 : bhh0;
        Br  = bi[c] + bh[c];
        Bz  = bi[Hh + c] + bh[Hh + c];
        Bin = bi[2*Hh + c];
        Bhn = bh[2*Hh + c];
    }

    float hp = 0.f;                        // register-carried h_prev (gate threads)

    for (int t = 0; t < Tt; ++t){
        // ---- per-lane A-fragment loads + fix + MFMA (no staging barrier) ----
        if (active){
            i32x4 av[8];                   // [ks*2 + half], 8 cols per ks
            const unsigned* ap[8];
            unsigned atag = 1u;
            bool have = true;              // loads issued / frags nonzero

            if (isL1){
                const unsigned* s0 = hseq0 + ((long)t * Bb + m*16) * (long)Hh;
                long r1 = BIG ? (long)(t-1) * BH : (long)((t-1) & 1) * BH;
                const unsigned* s1 = hseq1 + r1 + (long)(m*16) * Hh;
                unsigned tag1 = BIG ? 1u : (1u - (((unsigned)(t-1) >> 1) & 1u));
                if (w < 4){
                    // pipe: hseq0[t], cols C = w*128 + q*8 + ks*32 (< 512)
#pragma unroll
                    for (int ks = 0; ks < 4; ++ks){
                        int C = w*128 + q*8 + ks*32;
                        ap[ks*2]   = s0 + (long)r * Hh + C;
                        ap[ks*2+1] = ap[ks*2] + 4;
                    }
                    atag = 1u;
                } else {
                    // own recurrence: hseq1[t-1], cols C-512
#pragma unroll
                    for (int ks = 0; ks < 4; ++ks){
                        int C = (w-4)*128 + q*8 + ks*32;
                        ap[ks*2]   = s1 + (long)r * Hh + C;
                        ap[ks*2+1] = ap[ks*2] + 4;
                    }
                    atag = tag1;
                    if (t == 0) have = false;      // h1[-1] = 0
                }
                if (have){
#pragma unroll
                    for (int i = 0; i < 8; ++i) av[i] = *(const i32x4*)ap[i];
#pragma unroll
                    for (int i = 0; i < 8; ++i) fix4(ap[i], atag, av[i]);
                } else {
#pragma unroll
                    for (int i = 0; i < 8; ++i) av[i] = i32x4{0,0,0,0};
                }
            } else {
                if (w == 0){
                    // X[t] fp32 -> pack in-register (no wait, no tag)
                    const float* xb = X + ((long)(m*16 + r) * Tt + t) * DIN;
#pragma unroll
                    for (int ks = 0; ks < 4; ++ks){
                        int C = q*8 + ks*32;
                        f32x4 x0 = *(const f32x4*)(xb + C);
                        f32x4 x1 = *(const f32x4*)(xb + C + 4);
                        i32x4 p0, p1;
                        p0[0] = (int)pack_split(x0[0]); p0[1] = (int)pack_split(x0[1]);
                        p0[2] = (int)pack_split(x0[2]); p0[3] = (int)pack_split(x0[3]);
                        p1[0] = (int)pack_split(x1[0]); p1[1] = (int)pack_split(x1[1]);
                        p1[2] = (int)pack_split(x1[2]); p1[3] = (int)pack_split(x1[3]);
                        av[ks*2] = p0; av[ks*2+1] = p1;
                    }
                } else {
                    // recurrence: hseq0[t-1], cols C-128
                    const unsigned* s0 = hseq0 + ((long)(t-1) * Bb + m*16) * (long)Hh;
#pragma unroll
                    for (int ks = 0; ks < 4; ++ks){
                        int C = (w-1)*128 + q*8 + ks*32;
                        ap[ks*2]   = s0 + (long)r * Hh + C;
                        ap[ks*2+1] = ap[ks*2] + 4;
                    }
                    if (t == 0){
#pragma unroll
                        for (int i = 0; i < 8; ++i) av[i] = i32x4{0,0,0,0};
                    } else {
#pragma unroll
                        for (int i = 0; i < 8; ++i) av[i] = *(const i32x4*)ap[i];
#pragma unroll
                        for (int i = 0; i < 8; ++i) fix4(ap[i], 1u, av[i]);
                    }
                }
            }

            // ---- MFMA: this wave's K-slice, tiles {r, z, nx-or-nh} ----
            f32x4 a0 = {0.f,0.f,0.f,0.f}, a1 = a0, a2 = a0;
#pragma unroll
            for (int ks = 0; ks < 4; ++ks){
                unsigned uu[8];
                *(i32x4*)&uu[0] = av[ks*2];
                *(i32x4*)&uu[4] = av[ks*2+1];
                bf16x8 ah, al; make_afrag(uu, ah, al);
                a0 = MFMA16(ah, whi[ks][0], a0, 0,0,0);
                a0 = MFMA16(ah, wlo[ks][0], a0, 0,0,0);
                a0 = MFMA16(al, whi[ks][0], a0, 0,0,0);
                a1 = MFMA16(ah, whi[ks][1], a1, 0,0,0);
                a1 = MFMA16(ah, wlo[ks][1], a1, 0,0,0);
                a1 = MFMA16(al, whi[ks][1], a1, 0,0,0);
                a2 = MFMA16(ah, whi[ks][2], a2, 0,0,0);
                a2 = MFMA16(ah, wlo[ks][2], a2, 0,0,0);
                a2 = MFMA16(al, whi[ks][2], a2, 0,0,0);
            }
#pragma unroll
            for (int r4 = 0; r4 < 4; ++r4){
                int idx = (q*4 + r4)*PR + r;
                P[w][0][idx] = a0[r4];
                P[w][1][idx] = a1[r4];
                P[w][2][idx] = a2[r4];
            }
        }
        __syncthreads();

        // ---- reduce partials + gates -> direct tagged u32 agent store ----
        unsigned wtag = isL1 ? (BIG ? 1u : (1u - (((unsigned)t >> 1) & 1u))) : 1u;
        if (tid < 256){
            int bm = tid >> 4, n = tid & 15;
            int idx = bm * PR + n;
            float sr, sz, snx, snh;
            if (isL1){
                sr  = P[0][0][idx]+P[1][0][idx]+P[2][0][idx]+P[3][0][idx]
                    + P[4][0][idx]+P[5][0][idx]+P[6][0][idx]+P[7][0][idx];
                sz  = P[0][1][idx]+P[1][1][idx]+P[2][1][idx]+P[3][1][idx]
                    + P[4][1][idx]+P[5][1][idx]+P[6][1][idx]+P[7][1][idx];
                snx = P[0][2][idx]+P[1][2][idx]+P[2][2][idx]+P[3][2][idx];
                snh = P[4][2][idx]+P[5][2][idx]+P[6][2][idx]+P[7][2][idx];
            } else {
                sr  = P[0][0][idx]+P[1][0][idx]+P[2][0][idx]+P[3][0][idx]+P[4][0][idx];
                sz  = P[0][1][idx]+P[1][1][idx]+P[2][1][idx]+P[3][1][idx]+P[4][1][idx];
                snx = P[0][2][idx];
                snh = P[1][2][idx]+P[2][2][idx]+P[3][2][idx]+P[4][2][idx];
            }
            float rg = 1.f/(1.f + __expf(-(sr + Br)));
            float z  = 1.f/(1.f + __expf(-(sz + Bz)));
            float ee = __expf(2.f*(snx + Bin + rg*(snh + Bhn)));
            float nn = 1.f - 2.f/(ee + 1.f);
            float hnew = (1.f - z)*nn + z*hp;
            hp = hnew;
            unsigned pv = (pack_split(hnew) & ~1u) | wtag;
            unsigned* base = isL1
                ? hseq1 + (BIG ? (long)t * BH : (long)(t & 1) * BH)
                : hseq0 + (long)t * BH;
            ast32(base + (long)(m*16 + bm) * Hh + c0 + n, pv);
        }
        // post-gate barrier: guards P reuse across t and bounds run-ahead.
        __syncthreads();
    }

    // ---- FC epilogue: one layer1 block per m, validated reads ----
    if (isL1 && cb == 31){
        unsigned ftag = BIG ? 1u : (1u - (((unsigned)(Tt-1) >> 1) & 1u));
        const unsigned* hb = hseq1 + (BIG ? (long)(Tt-1) * BH : (long)((Tt-1) & 1) * BH);
        int half = lane >> 5, l5 = lane & 31;
        int b = m*16 + w*2 + half;
        const u64* hrow = (const u64*)(hb + (long)b * Hh);
        float p = 0.f;
#pragma unroll
        for (int i = 0; i < 8; ++i){
            int k = l5 + 32*i;
            u64 v = ald64(hrow + k);
            while (((((unsigned)v ^ ftag) | ((unsigned)(v >> 32) ^ ftag)) & 1u) != 0u){
                __builtin_amdgcn_s_sleep(1);
                v = ald64(hrow + k);
            }
            p += unpack_f32((unsigned)v) * fcW[2*k]
               + unpack_f32((unsigned)(v >> 32)) * fcW[2*k+1];
        }
#pragma unroll
        for (int off = 16; off > 0; off >>= 1) p += __shfl_xor(p, off);
        if (l5 == 0) out[b] = p + fcb[0];
    }
}

extern "C" void kernel_launch(void* const* d_in, const int* in_sizes, int n_in,
                              void* d_out, int out_size, void* d_ws, size_t ws_size,
                              hipStream_t stream) {
    const float* X    = (const float*)d_in[0];
    const float* Wih0 = (const float*)d_in[1];
    const float* Whh0 = (const float*)d_in[2];
    const float* bih0 = (const float*)d_in[3];
    const float* bhh0 = (const float*)d_in[4];
    const float* Wih1 = (const float*)d_in[5];
    const float* Whh1 = (const float*)d_in[6];
    const float* bih1 = (const float*)d_in[7];
    const float* bhh1 = (const float*)d_in[8];
    const float* fcW  = (const float*)d_in[9];
    const float* fcb  = (const float*)d_in[10];
    float* out = (float*)d_out;

    // ws: hseq0 64 MiB | hseq1 64 MiB (BIG) or 256 KiB ring. No flags, no memset:
    // harness poisons ws to 0xAA (bit0=0 = invalid) before every launch.
    unsigned* hseq0 = (unsigned*)d_ws;
    unsigned* hseq1 = hseq0 + (long)Tt * BH;
    size_t need_big = (size_t)2 * Tt * BH * 4;    // 128 MiB
    bool big = ws_size >= need_big;

    if (big)
        gru_main<true><<<256, 512, 0, stream>>>(X, Wih0, Whh0, bih0, bhh0,
                                                Wih1, Whh1, bih1, bhh1, fcW, fcb,
                                                out, hseq0, hseq1);
    else
        gru_main<false><<<256, 512, 0, stream>>>(X, Wih0, Whh0, bih0, bhh0,
                                                 Wih1, Whh1, bih1, bhh1, fcW, fcb,
                                                 out, hseq0, hseq1);
}

// Round 9
// 1702.033 us; speedup vs baseline: 1.7073x; 1.1367x over previous
//
#include <hip/hip_runtime.h>

// GRU B=64, T=512, IN=128, H=512, L=2, OUT=1 (fp32 in/out).
// R12: R9 verbatim with ONE change -- speculative staging loads are
// relaxed AGENT loads (2x u64 per 16B chunk) instead of plain cached
// dwordx4. Rationale (R9/R11 evidence): consumers always race producers,
// so the plain speculative load deposits a STALE line in the local XCD L2
// and forces a guaranteed second MALL RTT via the fix4 agent path -- a
// systematic 2-RTT-per-step detour. Agent-first reads the coherence point
// directly: 1 RTT in the common case. Initial loads are one-shot (not a
// retry loop) -- this is NOT the R7/R8 fixN flood; fix4 retry stays
// SERIALIZED per chunk (fabric rate-limiter).
// History: R9=1723us (best). R10 XCD remap=2906 (regression, reverted).
// R11 register-direct A-frags=1935 (regression: exchange wants dense
// staged loads; intra-block barriers/LDS are slack). R7/R8 fixN=storm.

constexpr int Bb = 64, Tt = 512, DIN = 128, Hh = 512;
constexpr int BH = Bb * Hh;
constexpr int S0 = 644;    // LDS A-row stride (u32), layer0: 128 x + 512 h + 4 pad
constexpr int S1 = 1028;   // layer1: 512 h0 + 512 h1 + 4 pad
constexpr int PR = 20;     // partials row stride: conflict-free (2-way) writes

typedef float  f32x4  __attribute__((ext_vector_type(4)));
typedef short  bf16x8 __attribute__((ext_vector_type(8)));
typedef int    i32x4  __attribute__((ext_vector_type(4)));
typedef unsigned long long u64;

#define MFMA16 __builtin_amdgcn_mfma_f32_16x16x32_bf16

__device__ __forceinline__ unsigned rne_bf16(unsigned xb){
    return (xb + 0x7FFFu + ((xb >> 16) & 1u)) >> 16;
}
__device__ __forceinline__ unsigned pack_split(float x){
    unsigned hb = rne_bf16(__float_as_uint(x));
    float hf = __uint_as_float(hb << 16);
    unsigned lb = rne_bf16(__float_as_uint(x - hf));
    return (hb << 16) | lb;
}
__device__ __forceinline__ float unpack_f32(unsigned u){
    return __uint_as_float(u & 0xFFFF0000u) + __uint_as_float(u << 16);
}

union FragU { unsigned w[4]; bf16x8 v; };

__device__ __forceinline__ void make_wfrag(const float* p, bf16x8& wh, bf16x8& wl){
    FragU hi, lo;
#pragma unroll
    for (int i = 0; i < 4; ++i){
        unsigned pa = pack_split(p[2*i]), pb = pack_split(p[2*i+1]);
        hi.w[i] = (pa >> 16) | (pb & 0xFFFF0000u);
        lo.w[i] = (pa & 0xFFFFu) | (pb << 16);
    }
    wh = hi.v; wl = lo.v;
}
// hi word = [b3,b2,a3,a2], lo word = [b1,b0,a1,a0] -- one v_perm_b32 each.
__device__ __forceinline__ void make_afrag(const unsigned* u, bf16x8& ah, bf16x8& al){
    FragU hi, lo;
#pragma unroll
    for (int i = 0; i < 4; ++i){
        unsigned a = u[2*i], b = u[2*i+1];
        hi.w[i] = __builtin_amdgcn_perm(b, a, 0x07060302u);
        lo.w[i] = __builtin_amdgcn_perm(b, a, 0x05040100u);
    }
    ah = hi.v; al = lo.v;
}

__device__ __forceinline__ u64 ald64(const u64* p){
    return __hip_atomic_load(p, __ATOMIC_RELAXED, __HIP_MEMORY_SCOPE_AGENT);
}
__device__ __forceinline__ void ast64(u64* p, u64 v){
    __hip_atomic_store(p, v, __ATOMIC_RELAXED, __HIP_MEMORY_SCOPE_AGENT);
}
// 16B speculative read via two relaxed agent loads (bypasses stale-capable
// plain-cached path; goes straight to the coherence point).
__device__ __forceinline__ i32x4 ald128(const unsigned* p){
    u64 a = ald64((const u64*)p);
    u64 b = ald64((const u64*)p + 1);
    i32x4 v;
    v[0] = (int)(unsigned)a; v[1] = (int)(unsigned)(a >> 32);
    v[2] = (int)(unsigned)b; v[3] = (int)(unsigned)(b >> 32);
    return v;
}

// all 4 words must have bit0 == tag
__device__ __forceinline__ bool bad4(const i32x4& v, unsigned tag){
    unsigned x = ((unsigned)v[0] ^ tag) | ((unsigned)v[1] ^ tag)
               | ((unsigned)v[2] ^ tag) | ((unsigned)v[3] ^ tag);
    return (x & 1u) != 0u;
}
// retry path: agent loads, SERIALIZED per chunk (rate limiter -- R7/R8).
__device__ __forceinline__ void fix4(const unsigned* p, unsigned tag, i32x4& v){
    if (bad4(v, tag)){
        for (;;){
            u64 a = ald64((const u64*)p);
            u64 b = ald64((const u64*)p + 1);
            v[0] = (int)(unsigned)a; v[1] = (int)(unsigned)(a >> 32);
            v[2] = (int)(unsigned)b; v[3] = (int)(unsigned)(b >> 32);
            if (!bad4(v, tag)) break;
            __builtin_amdgcn_s_sleep(1);
        }
    }
}

template<bool BIG>
__global__ __launch_bounds__(512, 1) void gru_main(
    const float* __restrict__ X,
    const float* __restrict__ Wih0, const float* __restrict__ Whh0,
    const float* __restrict__ bih0, const float* __restrict__ bhh0,
    const float* __restrict__ Wih1, const float* __restrict__ Whh1,
    const float* __restrict__ bih1, const float* __restrict__ bhh1,
    const float* __restrict__ fcW, const float* __restrict__ fcb,
    float* __restrict__ out,
    unsigned* hseq0, unsigned* hseq1)
{
    // Kill stale clean L1/L2 lines left from the previous graph replay.
    __builtin_amdgcn_fence(__ATOMIC_ACQUIRE, "agent");

    __shared__ unsigned Alds[16 * S1];
    __shared__ float P[8][3][16 * PR];
    __shared__ unsigned hout[256];

    const int tid  = threadIdx.x;
    const int lane = tid & 63;
    const int w    = tid >> 6;
    const bool isL1 = blockIdx.x >= 128;
    const int lb = isL1 ? (int)blockIdx.x - 128 : (int)blockIdx.x;
    const int m  = lb >> 5;                // batch tile 0..3
    const int cb = lb & 31;                // col-block 0..31
    const int c0 = cb * 16;
    const int STR  = isL1 ? S1 : S0;
    const int HOFF = isL1 ? 512 : 128;

    const bool active = isL1 || (w < 5);   // layer0 K=640 -> 5 waves x 128

    // ---- register-resident weight fragments (hi/lo split-bf16) ----
    bf16x8 whi[4][3], wlo[4][3];
    if (active){
        const int n = lane & 15;
#pragma unroll
        for (int ks = 0; ks < 4; ++ks){
            int kq = w * 128 + ks * 32 + (lane >> 4) * 8;
            const float* src; long kloc, rowlen;
            if (isL1){
                if (kq < 512){ src = Wih1; kloc = kq; } else { src = Whh1; kloc = kq - 512; }
                rowlen = 512;
            } else {
                if (kq < 128){ src = Wih0; kloc = kq; rowlen = 128; }
                else         { src = Whh0; kloc = kq - 128; rowlen = 512; }
            }
#pragma unroll
            for (int g = 0; g < 3; ++g){
                long row = (long)g * Hh + c0 + n;
                make_wfrag(src + row * rowlen + kloc, whi[ks][g], wlo[ks][g]);
            }
        }
    }
    // ---- biases for epilogue ----
    float Br = 0.f, Bz = 0.f, Bin = 0.f, Bhn = 0.f;
    if (tid < 256){
        int c = c0 + (tid & 15);
        const float* bi = isL1 ? bih1 : bih0;
        const float* bh = isL1 ? bhh1 : bhh0;
        Br  = bi[c] + bh[c];
        Bz  = bi[Hh + c] + bh[Hh + c];
        Bin = bi[2*Hh + c];
        Bhn = bh[2*Hh + c];
    }

    for (int t = 0; t < Tt; ++t){
        // ---- staging: agent-first speculative loads + serialized fix-up ----
        if (isL1){
            const unsigned* s0 = hseq0 + ((long)t * Bb + m*16) * (long)Hh;
            long r1 = BIG ? (long)(t-1) * BH : (long)((t-1) & 1) * BH;
            const unsigned* s1 = hseq1 + r1 + (long)(m*16) * Hh;
            unsigned tag1 = BIG ? 1u : (1u - (((unsigned)(t-1) >> 1) & 1u));
            const unsigned* a0[4]; const unsigned* a1[4];
            i32x4 v0[4], v1[4];
#pragma unroll
            for (int it = 0; it < 4; ++it){
                int j = it*512 + tid; int row = j >> 7, col = (j & 127) * 4;
                a0[it] = s0 + (long)row * Hh + col;
                v0[it] = ald128(a0[it]);
            }
            if (t > 0){
#pragma unroll
                for (int it = 0; it < 4; ++it){
                    int j = it*512 + tid; int row = j >> 7, col = (j & 127) * 4;
                    a1[it] = s1 + (long)row * Hh + col;
                    v1[it] = ald128(a1[it]);
                }
            }
#pragma unroll
            for (int it = 0; it < 4; ++it) fix4(a0[it], 1u, v0[it]);
            if (t > 0){
#pragma unroll
                for (int it = 0; it < 4; ++it) fix4(a1[it], tag1, v1[it]);
            } else {
#pragma unroll
                for (int it = 0; it < 4; ++it) v1[it] = i32x4{0,0,0,0};
            }
#pragma unroll
            for (int it = 0; it < 4; ++it){
                int j = it*512 + tid; int row = j >> 7, col = (j & 127) * 4;
                *(i32x4*)(Alds + row * S1 + col) = v0[it];
                *(i32x4*)(Alds + row * S1 + 512 + col) = v1[it];
            }
        } else {
            // X[t] fp32 (cached input) -> pack on the fly
            {
                int row = tid >> 5, c4 = (tid & 31) * 4;
                f32x4 xv = *(const f32x4*)(X + ((long)(m*16 + row) * Tt + t) * DIN + c4);
                i32x4 pv;
                pv[0] = (int)pack_split(xv[0]);
                pv[1] = (int)pack_split(xv[1]);
                pv[2] = (int)pack_split(xv[2]);
                pv[3] = (int)pack_split(xv[3]);
                *(i32x4*)(Alds + row * S0 + c4) = pv;
            }
            if (t > 0){
                const unsigned* s0 = hseq0 + ((long)(t-1) * Bb + m*16) * (long)Hh;
                const unsigned* a0[4]; i32x4 v0[4];
#pragma unroll
                for (int it = 0; it < 4; ++it){
                    int j = it*512 + tid; int row = j >> 7, col = (j & 127) * 4;
                    a0[it] = s0 + (long)row * Hh + col;
                    v0[it] = ald128(a0[it]);
                }
#pragma unroll
                for (int it = 0; it < 4; ++it) fix4(a0[it], 1u, v0[it]);
#pragma unroll
                for (int it = 0; it < 4; ++it){
                    int j = it*512 + tid; int row = j >> 7, col = (j & 127) * 4;
                    *(i32x4*)(Alds + row * S0 + 128 + col) = v0[it];
                }
            } else {
#pragma unroll
                for (int it = 0; it < 8; ++it){
                    int j = it*512 + tid;
                    *(u64*)(Alds + (j >> 8) * S0 + 128 + (j & 255) * 2) = 0ULL;
                }
            }
        }
        __syncthreads();

        // ---- MFMA: this wave's K-slice, tiles {r, z, nx-or-nh} ----
        if (active){
            f32x4 a0 = {0.f,0.f,0.f,0.f}, a1 = a0, a2 = a0;
            const unsigned* arow = Alds + (lane & 15) * STR + w * 128 + (lane >> 4) * 8;
#pragma unroll
            for (int ks = 0; ks < 4; ++ks){
                unsigned uu[8];
                *(i32x4*)&uu[0] = *(const i32x4*)(arow + ks*32);
                *(i32x4*)&uu[4] = *(const i32x4*)(arow + ks*32 + 4);
                bf16x8 ah, al; make_afrag(uu, ah, al);
                a0 = MFMA16(ah, whi[ks][0], a0, 0,0,0);
                a0 = MFMA16(ah, wlo[ks][0], a0, 0,0,0);
                a0 = MFMA16(al, whi[ks][0], a0, 0,0,0);
                a1 = MFMA16(ah, whi[ks][1], a1, 0,0,0);
                a1 = MFMA16(ah, wlo[ks][1], a1, 0,0,0);
                a1 = MFMA16(al, whi[ks][1], a1, 0,0,0);
                a2 = MFMA16(ah, whi[ks][2], a2, 0,0,0);
                a2 = MFMA16(ah, wlo[ks][2], a2, 0,0,0);
                a2 = MFMA16(al, whi[ks][2], a2, 0,0,0);
            }
            int q = lane >> 4, n = lane & 15;
#pragma unroll
            for (int r4 = 0; r4 < 4; ++r4){
                int idx = (q*4 + r4)*PR + n;
                P[w][0][idx] = a0[r4];
                P[w][1][idx] = a1[r4];
                P[w][2][idx] = a2[r4];
            }
        }
        __syncthreads();

        // ---- reduce partials + gates -> tagged packed h into LDS ----
        unsigned wtag = isL1 ? (BIG ? 1u : (1u - (((unsigned)t >> 1) & 1u))) : 1u;
        if (tid < 256){
            int bm = tid >> 4, n = tid & 15;
            int idx = bm * PR + n;
            float sr, sz, snx, snh;
            if (isL1){
                sr  = P[0][0][idx]+P[1][0][idx]+P[2][0][idx]+P[3][0][idx]
                    + P[4][0][idx]+P[5][0][idx]+P[6][0][idx]+P[7][0][idx];
                sz  = P[0][1][idx]+P[1][1][idx]+P[2][1][idx]+P[3][1][idx]
                    + P[4][1][idx]+P[5][1][idx]+P[6][1][idx]+P[7][1][idx];
                snx = P[0][2][idx]+P[1][2][idx]+P[2][2][idx]+P[3][2][idx];
                snh = P[4][2][idx]+P[5][2][idx]+P[6][2][idx]+P[7][2][idx];
            } else {
                sr  = P[0][0][idx]+P[1][0][idx]+P[2][0][idx]+P[3][0][idx]+P[4][0][idx];
                sz  = P[0][1][idx]+P[1][1][idx]+P[2][1][idx]+P[3][1][idx]+P[4][1][idx];
                snx = P[0][2][idx];
                snh = P[1][2][idx]+P[2][2][idx]+P[3][2][idx]+P[4][2][idx];
            }
            float r  = 1.f/(1.f + __expf(-(sr + Br)));
            float z  = 1.f/(1.f + __expf(-(sz + Bz)));
            float ee = __expf(2.f*(snx + Bin + r*(snh + Bhn)));
            float nn = 1.f - 2.f/(ee + 1.f);
            float hp = unpack_f32(Alds[bm*STR + HOFF + c0 + n]);
            float hnew = (1.f - z)*nn + z*hp;
            hout[tid] = (pack_split(hnew) & ~1u) | wtag;   // hout[bm*16 + n]
        }
        __syncthreads();

        // ---- agent u64 stores; NO ack wait, NO flag — sail into t+1 ----
        if (tid < 128){
            int bm = tid >> 3, k = (tid & 7) * 2;
            u64 v = (u64)hout[bm*16 + k] | ((u64)hout[bm*16 + k + 1] << 32);
            unsigned* base = isL1
                ? hseq1 + (BIG ? (long)t * BH : (long)(t & 1) * BH)
                : hseq0 + (long)t * BH;
            ast64((u64*)(base + (long)(m*16 + bm) * Hh + c0 + k), v);
        }
    }

    // ---- FC epilogue: one layer1 block per m, validated reads ----
    if (isL1 && cb == 31){
        unsigned ftag = BIG ? 1u : (1u - (((unsigned)(Tt-1) >> 1) & 1u));
        const unsigned* hb = hseq1 + (BIG ? (long)(Tt-1) * BH : (long)((Tt-1) & 1) * BH);
        int half = lane >> 5, l5 = lane & 31;
        int b = m*16 + w*2 + half;
        const u64* hrow = (const u64*)(hb + (long)b * Hh);
        float p = 0.f;
#pragma unroll
        for (int i = 0; i < 8; ++i){
            int k = l5 + 32*i;
            u64 v = ald64(hrow + k);
            while (((((unsigned)v ^ ftag) | ((unsigned)(v >> 32) ^ ftag)) & 1u) != 0u){
                __builtin_amdgcn_s_sleep(1);
                v = ald64(hrow + k);
            }
            p += unpack_f32((unsigned)v) * fcW[2*k]
               + unpack_f32((unsigned)(v >> 32)) * fcW[2*k+1];
        }
#pragma unroll
        for (int off = 16; off > 0; off >>= 1) p += __shfl_xor(p, off);
        if (l5 == 0) out[b] = p + fcb[0];
    }
}

extern "C" void kernel_launch(void* const* d_in, const int* in_sizes, int n_in,
                              void* d_out, int out_size, void* d_ws, size_t ws_size,
                              hipStream_t stream) {
    const float* X    = (const float*)d_in[0];
    const float* Wih0 = (const float*)d_in[1];
    const float* Whh0 = (const float*)d_in[2];
    const float* bih0 = (const float*)d_in[3];
    const float* bhh0 = (const float*)d_in[4];
    const float* Wih1 = (const float*)d_in[5];
    const float* Whh1 = (const float*)d_in[6];
    const float* bih1 = (const float*)d_in[7];
    const float* bhh1 = (const float*)d_in[8];
    const float* fcW  = (const float*)d_in[9];
    const float* fcb  = (const float*)d_in[10];
    float* out = (float*)d_out;

    // ws: hseq0 64 MiB | hseq1 64 MiB (BIG) or 256 KiB ring. No flags, no memset:
    // harness poisons ws to 0xAA (bit0=0 = invalid) before every launch.
    unsigned* hseq0 = (unsigned*)d_ws;
    unsigned* hseq1 = hseq0 + (long)Tt * BH;
    size_t need_big = (size_t)2 * Tt * BH * 4;    // 128 MiB
    bool big = ws_size >= need_big;

    if (big)
        gru_main<true><<<256, 512, 0, stream>>>(X, Wih0, Whh0, bih0, bhh0,
                                                Wih1, Whh1, bih1, bhh1, fcW, fcb,
                                                out, hseq0, hseq1);
    else
        gru_main<false><<<256, 512, 0, stream>>>(X, Wih0, Whh0, bih0, bhh0,
                                                 Wih1, Whh1, bih1, bhh1, fcW, fcb,
                                                 out, hseq0, hseq1);
}